// Round 4
// baseline (1236.547 us; speedup 1.0000x reference)
//
#include <hip/hip_runtime.h>
#include <stdint.h>

// TrajEncoder: embedding gather + LSTM(D=128,H=256) over T=512, output h at valid_len-1.
// 64 clusters (one per batch) x 4 WGs; each WG owns 64 hidden units (256 gate rows).
// R4: (1) dot relayout 4 rows x 16 cols/thread -> 3 ds_read_b128/thread/step (was 12),
//     DPP 16-lane reduction (VALU, off the LDS pipe);
// (2) same-XCD L2 exchange: cluster members {b,b+64,b+128,b+192} all = b (mod 8) -> same
//     XCD under round-robin. Producer dual-stores packed h (sc0 L2 path + agent L3 path);
//     pollers spin on the sc0 buffer, bounded, with permanent per-thread fallback to the
//     agent buffer -> correct regardless of placement/sc0 semantics.
// Epoch encoding: h in (-1,1) => bit14 of each f16 half clear; ~pk sets it. memset 0xFF
// rejects at phase-0 steps (the only steps that can observe init data).

#define BB 64
#define TT 512
#define DD 128
#define HH 256

typedef __fp16 half2v __attribute__((ext_vector_type(2)));

__device__ __forceinline__ uint32_t pk_f16(float lo, float hi) {
    half2v h = __builtin_amdgcn_cvt_pkrtz(lo, hi);
    return __builtin_bit_cast(uint32_t, h);
}

__device__ __forceinline__ float dot2(uint32_t a, uint32_t b, float acc) {
#if __has_builtin(__builtin_amdgcn_fdot2)
    return __builtin_amdgcn_fdot2(__builtin_bit_cast(half2v, a),
                                  __builtin_bit_cast(half2v, b), acc, false);
#else
    half2v av = __builtin_bit_cast(half2v, a);
    half2v bv = __builtin_bit_cast(half2v, b);
    acc += (float)av[0] * (float)bv[0];
    acc += (float)av[1] * (float)bv[1];
    return acc;
#endif
}

// acc += acc[perm(lane)] via DPP; valid at lane cg==0 after the 4-step chain.
template<int CTRL>
__device__ __forceinline__ float dpp_add(float a) {
    int m = __builtin_amdgcn_update_dpp(0, __builtin_bit_cast(int, a), CTRL, 0xF, 0xF, false);
    return a + __builtin_bit_cast(float, m);
}

// L1-bypass, L2-coherent ops for same-XCD exchange.
__device__ __forceinline__ uint32_t load_sc0(const uint32_t* p) {
    uint32_t v;
    asm volatile("global_load_dword %0, %1, off sc0\n\ts_waitcnt vmcnt(0)"
                 : "=v"(v) : "v"(p) : "memory");
    return v;
}
__device__ __forceinline__ void store_sc0(uint32_t* p, uint32_t v) {
    asm volatile("global_store_dword %0, %1, off sc0" :: "v"(p), "v"(v) : "memory");
}

__device__ __forceinline__ float fsig(float x)  { return 1.f / (1.f + __expf(-x)); }
__device__ __forceinline__ float ftanh(float x) { return 1.f - 2.f / (__expf(2.f * x) + 1.f); }

__global__ __launch_bounds__(1024, 4)
void lstm_cluster_kernel(const int* __restrict__ path, const int* __restrict__ vlen,
                         const float* __restrict__ emb, const float* __restrict__ Wih,
                         const float* __restrict__ Whh, const float* __restrict__ bih,
                         const float* __restrict__ bhh, float* __restrict__ out,
                         uint32_t* hxF /* sc0/L2 exchange [2][BB][128] */,
                         uint32_t* hxA /* agent/L3 exchange [2][BB][128] */) {
    const int b   = blockIdx.x & (BB - 1);
    const int k   = blockIdx.x >> 6;      // cluster member: owns h units [64k,64k+64)
    const int tid = threadIdx.x;
    const int rg  = tid >> 4;             // row-group 0..63 (4 gate rows each)
    const int cg  = tid & 15;             // col-group 0..15 (16 h cols / 8 x cols)

    __shared__ uint32_t h_pk[16][12];     // packed h: [group][8 used + 4 pad] (align+bank)
    __shared__ uint32_t x_pk[2][16][12];  // packed x_t, double buffered: [g][4 used + 8 pad]
    __shared__ float    G[256];           // gate pre-activations (bias included)
    __shared__ int      path_l[TT];

    // ---- weight slices -> packed f16 registers (4 rows x 16/8 cols per thread) ----
    uint32_t whh[32], wih[16];
    float    bias[4];
#pragma unroll
    for (int rr = 0; rr < 4; ++rr) {
        const int row  = (rg << 2) + rr;                       // local gate row 0..255
        const int grow = ((row >> 6) << 8) + (k << 6) + (row & 63);
        const float* wr = Whh + grow * HH + (cg << 4);
#pragma unroll
        for (int c = 0; c < 8; ++c) whh[rr * 8 + c] = pk_f16(wr[2 * c], wr[2 * c + 1]);
        const float* wr2 = Wih + grow * DD + (cg << 3);
#pragma unroll
        for (int c = 0; c < 4; ++c) wih[rr * 4 + c] = pk_f16(wr2[2 * c], wr2[2 * c + 1]);
        bias[rr] = bih[grow] + bhh[grow];
    }
    const int L = vlen[b];

    if (tid < TT)  path_l[tid] = path[b * TT + tid];
    if (tid < 192) ((uint32_t*)h_pk)[tid] = 0u;   // h_0 = 0 (pads included)
    __syncthreads();

    // waves 2-3 own the x pipeline: stage x_0, prefetch x_1
    float xr_next = 0.f;
    if (tid >= 128 && tid < 256) {
        int e = tid - 128;
        float x0 = emb[(size_t)path_l[0] * DD + e];
        float hi = __shfl_xor(x0, 1);
        if (!(e & 1)) { int j = e >> 1; x_pk[0][j >> 2][j & 3] = pk_f16(x0, hi); }
        xr_next = emb[(size_t)path_l[L > 1 ? 1 : 0] * DD + e];
    }
    float c_state = 0.f;
    bool  fast_ok = true;                 // per-thread sc0-path health (pollers only)
    __syncthreads();

    for (int t = 0; t < L; ++t) {
        const int slot  = t & 1;
        const int phase = (t >> 1) & 1;
        const uint32_t want = phase ? 0x40004000u : 0u;

        // (B) dots: 4 rows x (16 h cols + 8 x cols); LDS = 3 x ds_read_b128
        const uint4 hv0 = *(const uint4*)&h_pk[cg][0];
        const uint4 hv1 = *(const uint4*)&h_pk[cg][4];
        const uint4 xv  = *(const uint4*)&x_pk[slot][cg][0];
        float acc[4];
#pragma unroll
        for (int rr = 0; rr < 4; ++rr) {
            float a = 0.f;
            a = dot2(whh[rr * 8 + 0], hv0.x, a);
            a = dot2(whh[rr * 8 + 1], hv0.y, a);
            a = dot2(whh[rr * 8 + 2], hv0.z, a);
            a = dot2(whh[rr * 8 + 3], hv0.w, a);
            a = dot2(whh[rr * 8 + 4], hv1.x, a);
            a = dot2(whh[rr * 8 + 5], hv1.y, a);
            a = dot2(whh[rr * 8 + 6], hv1.z, a);
            a = dot2(whh[rr * 8 + 7], hv1.w, a);
            a = dot2(wih[rr * 4 + 0], xv.x, a);
            a = dot2(wih[rr * 4 + 1], xv.y, a);
            a = dot2(wih[rr * 4 + 2], xv.z, a);
            a = dot2(wih[rr * 4 + 3], xv.w, a);
            // 16-lane reduce: quad xor1, xor2, then row_ror:4, row_ror:8 (valid at cg==0)
            a = dpp_add<0xB1>(a);
            a = dpp_add<0x4E>(a);
            a = dpp_add<0x124>(a);
            a = dpp_add<0x128>(a);
            acc[rr] = a + bias[rr];
        }
        if (cg == 0) *(float4*)&G[rg << 2] = make_float4(acc[0], acc[1], acc[2], acc[3]);
        __syncthreads();

        // ---- role phase: wave0 pointwise+publish | waves2-3 x stage | waves14-15 poll ----
        if (tid < 64) {
            float gi = fsig(G[tid]);
            float gf = fsig(G[64 + tid]);
            float gg = ftanh(G[128 + tid]);
            float go = fsig(G[192 + tid]);
            c_state  = gf * c_state + gi * gg;
            float h  = go * ftanh(c_state);
            if (t == L - 1) out[b * HH + (k << 6) + tid] = h;
            float h1 = __shfl_xor(h, 1);
            if (!(tid & 1)) {
                uint32_t pk = pk_f16(h, h1);
                int jj = (k << 5) + (tid >> 1);               // u32 index 0..127
                h_pk[jj >> 3][jj & 7] = pk;                   // own slice: LDS only
                uint32_t enc = phase ? ~pk : pk;
                int idx = (slot * BB + b) * 128 + jj;
                store_sc0(hxF + idx, enc);                    // fast: same-XCD L2
                __hip_atomic_store(hxA + idx, enc,
                                   __ATOMIC_RELAXED, __HIP_MEMORY_SCOPE_AGENT);
            }
        } else if (tid >= 128 && tid < 256) {
            int e = tid - 128;
            float hi = __shfl_xor(xr_next, 1);
            if (!(e & 1)) { int j = e >> 1; x_pk[slot ^ 1][j >> 2][j & 3] = pk_f16(xr_next, hi); }
            int tpf = (t + 2 < TT) ? t + 2 : TT - 1;
            xr_next = emb[(size_t)path_l[tpf] * DD + e];      // prefetch x_{t+2}
        } else if (tid >= 896 && tid < 992 && t < L - 1) {
            int j  = tid - 896;                               // 96 remote u32s
            int qq = j >> 5; if (qq >= k) ++qq;               // skip own quarter
            int c  = j & 31;
            const int idx = (slot * BB + b) * 128 + (qq << 5) + c;
            uint32_t v; bool got = false;
            if (fast_ok) {
                int bound = (t == 0) ? 5000 : 1000;
                do {
                    v = load_sc0(hxF + idx);
                    got = ((v & 0x40004000u) == want);
                } while (!got && --bound);
                if (!got) fast_ok = false;                    // permanent fallback
            }
            if (!got) {
                int spins = 0;
                do {
                    v = __hip_atomic_load(hxA + idx, __ATOMIC_RELAXED,
                                          __HIP_MEMORY_SCOPE_AGENT);
                } while ((v & 0x40004000u) != want && ++spins < (1 << 20));
            }
            uint32_t d = phase ? ~v : v;
            int jj = (qq << 5) + c;
            h_pk[jj >> 3][jj & 7] = d;
        }
        __syncthreads();   // h_pk / x_pk ready for next step
    }
}

extern "C" void kernel_launch(void* const* d_in, const int* in_sizes, int n_in,
                              void* d_out, int out_size, void* d_ws, size_t ws_size,
                              hipStream_t stream) {
    const int*   path = (const int*)d_in[0];
    const int*   vlen = (const int*)d_in[1];
    const float* emb  = (const float*)d_in[2];
    const float* Wih  = (const float*)d_in[3];
    const float* Whh  = (const float*)d_in[4];
    const float* bih  = (const float*)d_in[5];
    const float* bhh  = (const float*)d_in[6];

    uint32_t* hxA = (uint32_t*)d_ws;                  // [2][64][128] agent/L3 buffer
    uint32_t* hxF = hxA + 2 * BB * 128;               // [2][64][128] sc0/L2 buffer
    // 0xFF...: bit14 set in both halves -> rejected by phase-0 predicate (steps 0/1,
    // the only steps that can observe init data). Re-done every launch (128 KB).
    (void)hipMemsetAsync(d_ws, 0xFF, (size_t)4 * BB * 128 * sizeof(uint32_t), stream);
    lstm_cluster_kernel<<<256, 1024, 0, stream>>>(path, vlen, emb, Wih, Whh, bih, bhh,
                                                  (float*)d_out, hxF, hxA);
}